// Round 15
// baseline (96.281 us; speedup 1.0000x reference)
//
#include <hip/hip_runtime.h>
#include <hip/hip_bf16.h>
#include <cstdint>
#include <cstddef>

typedef __attribute__((ext_vector_type(8))) short bf16x8;
typedef __attribute__((ext_vector_type(4))) float f32x4;
typedef unsigned short u16;
typedef unsigned int u32;

#define DEV static __device__ __forceinline__

constexpr int Sc = 1024, DMc = 1024, Hc = 16, DKc = 64;

DEV u16 f2bf(float f) {
  u32 u = __float_as_uint(f);
  return (u16)((u + 0x7FFFu + ((u >> 16) & 1u)) >> 16);
}
DEV float bf2f(u16 h) { return __uint_as_float(((u32)h) << 16); }

// async global->LDS: 16B/lane, LDS dest = wave-uniform base + lane*16
#define GLDS16(g, l)                                                        \
  __builtin_amdgcn_global_load_lds(                                         \
      (const __attribute__((address_space(1))) void*)(g),                   \
      (__attribute__((address_space(3))) void*)(l), 16, 0, 0)

// ---------------- f32 -> bf16 + chunk-swizzle conversion ----------------
// Flat-packed: 8 jobs, job boundaries multiples of 256 chunks.
// Within each 64-elem (128B) block, 16B chunk c stored at c ^ (row & 7).
// Chunks in [nreal, nchunk) write zeros (Er spare row).
struct CvtJob { const float* in; u16* out; int rsh; int nreal; };
struct CvtArgs { CvtJob j[8]; int cum[8]; };

__global__ __launch_bounds__(256) void cvt_kernel(CvtArgs a) {
  int g = (int)(blockIdx.x * 256 + threadIdx.x);
  int jb = 0, base = 0;
  #pragma unroll
  for (int k = 0; k < 7; ++k) {
    bool m = g >= a.cum[k];
    jb += m ? 1 : 0;
    base = m ? a.cum[k] : base;
  }
  CvtJob job = a.j[jb];
  int ci = g - base;
  bf16x8 o = {};
  if (ci < job.nreal) {
    const float* src = job.in + (size_t)ci * 8;
    float4 v0 = *(const float4*)src;
    float4 v1 = *(const float4*)(src + 4);
    o[0] = (short)f2bf(v0.x); o[1] = (short)f2bf(v0.y);
    o[2] = (short)f2bf(v0.z); o[3] = (short)f2bf(v0.w);
    o[4] = (short)f2bf(v1.x); o[5] = (short)f2bf(v1.y);
    o[6] = (short)f2bf(v1.z); o[7] = (short)f2bf(v1.w);
  }
  int row = ci >> job.rsh;
  int co = (ci & ~7) | ((ci & 7) ^ (row & 7));
  *(bf16x8*)(job.out + (size_t)co * 8) = o;
}

// ---------------- GEMM: C = A(MxK) * W(NxK)^T + bias, K=1024 -------------
// (R12-verbatim: chunk-swizzled operands, GLDS16 staging, XCD-aware maps,
//  MODE 1 = out-proj with fused Opart merge.)
struct GemmJob { const u16* A; const u16* W; const float* bias; void* out; const float* aux; };
struct GemmArgs { GemmJob p[3]; };

template<int BM, int BN, int MODE>
__global__ __launch_bounds__(256, 2) void gemm_bt(GemmArgs G) {
  constexpr int MI = BM / 32, NI = BN / 32;
  __shared__ __align__(16) u16 sA[2][BM * 64];
  __shared__ __align__(16) u16 sB[2][BN * 64];
  const int tid = threadIdx.x, lane = tid & 63, w = tid >> 6;
  const int cl = lane & 15, rg = lane >> 4;
  const int srow = lane >> 3, schk = lane & 7;
  int z, m0, n0;
  if (MODE == 0) {
    int id = blockIdx.x;
    if (id < 512) {
      z = id >> 8;
      int r = id & 255, xcd = r & 7, t = r >> 3;
      m0 = (xcd * 4 + (t & 3)) * 64;
      n0 = (t >> 2) * 128;
    } else {
      z = 2;
      int r = id - 512, xcd = r & 7, t = r >> 3;
      n0 = (xcd * 2 + (t & 1)) * 128;
      m0 = (t >> 1) * 64;
    }
  } else {
    z = 0;
    int id = blockIdx.x, xcd = id & 7, t = id >> 3;
    m0 = (xcd * 4 + (t & 3)) * 64;
    n0 = (t >> 2) * 64;
  }
  GemmJob P = G.p[z];
  constexpr int K = 1024;
  const int wm = (w >> 1) * (BM / 2), wn = (w & 1) * (BN / 2);
  f32x4 acc[MI][NI] = {};

  bf16x8 ma[2][2];
  float  ml[2][2];

  auto stage = [&](int kt, int b) {
    if (MODE == 0) {
      const u16* Ab = P.A + (size_t)m0 * K + kt * 64;
      #pragma unroll
      for (int i = 0; i < BM / 32; ++i)
        GLDS16(Ab + (size_t)(i * 32 + w * 8 + srow) * K + schk * 8, &sA[b][(i * 32 + w * 8) * 64]);
    } else {
      #pragma unroll
      for (int i = 0; i < 2; ++i) {
        int ch = i * 256 + tid, row = ch >> 3, c = ch & 7;
        int rgl = m0 + row, bb = rgl >> 10, s = rgl & 1023;
        const u16* o0 = P.A + ((size_t)(bb * 16 + kt) * 1024 + s) * 64 + c * 8;
        ma[i][0] = *(const bf16x8*)o0;
        ma[i][1] = *(const bf16x8*)(o0 + (size_t)32 * 1024 * 64);
        ml[i][0] = P.aux[(size_t)(bb * 16 + kt) * 1024 + s];
        ml[i][1] = P.aux[(size_t)(32 + bb * 16 + kt) * 1024 + s];
      }
    }
    const u16* Wb = P.W + (size_t)n0 * K + kt * 64;
    #pragma unroll
    for (int i = 0; i < BN / 32; ++i)
      GLDS16(Wb + (size_t)(i * 32 + w * 8 + srow) * K + schk * 8, &sB[b][(i * 32 + w * 8) * 64]);
  };

  auto commit = [&](int b) {
    #pragma unroll
    for (int i = 0; i < 2; ++i) {
      int ch = i * 256 + tid, row = ch >> 3, c = ch & 7;
      float rinv = 1.0f / (ml[i][0] + ml[i][1]);
      bf16x8 v8;
      #pragma unroll
      for (int e = 0; e < 8; ++e)
        v8[e] = (short)f2bf((bf2f((u16)ma[i][0][e]) + bf2f((u16)ma[i][1][e])) * rinv);
      *(bf16x8*)(sA[b] + row * 64 + (c ^ (row & 7)) * 8) = v8;
    }
  };

  stage(0, 0);
  if (MODE == 1) commit(0);
  for (int kt = 0; kt < 16; ++kt) {
    __syncthreads();
    const int b = kt & 1;
    if (kt < 15) stage(kt + 1, b ^ 1);
    const u16* A_ = sA[b];
    const u16* B_ = sB[b];
    #pragma unroll
    for (int kk = 0; kk < 2; ++kk) {
      bf16x8 af[MI], bfr[NI];
      #pragma unroll
      for (int mi = 0; mi < MI; ++mi) {
        int row = wm + mi * 16 + cl;
        af[mi] = *(const bf16x8*)(A_ + row * 64 + ((kk * 4 + rg) ^ (row & 7)) * 8);
      }
      #pragma unroll
      for (int ni = 0; ni < NI; ++ni) {
        int row = wn + ni * 16 + cl;
        bfr[ni] = *(const bf16x8*)(B_ + row * 64 + ((kk * 4 + rg) ^ (row & 7)) * 8);
      }
      #pragma unroll
      for (int mi = 0; mi < MI; ++mi)
        #pragma unroll
        for (int ni = 0; ni < NI; ++ni)
          acc[mi][ni] = __builtin_amdgcn_mfma_f32_16x16x32_bf16(af[mi], bfr[ni], acc[mi][ni], 0, 0, 0);
    }
    if (MODE == 1 && kt < 15) commit(b ^ 1);
  }
  #pragma unroll
  for (int mi = 0; mi < MI; ++mi) {
    #pragma unroll
    for (int ni = 0; ni < NI; ++ni) {
      #pragma unroll
      for (int j = 0; j < 4; ++j) {
        int m = m0 + wm + mi * 16 + rg * 4 + j;
        int n = n0 + wn + ni * 16 + cl;
        if (MODE == 1) {
          ((float*)P.out)[(size_t)m * DMc + n] = acc[mi][ni][j] + P.bias[n];
        } else if (z < 2) {
          float v = acc[mi][ni][j] + P.bias[n];
          int h = n >> 6, d = n & 63;
          int c2 = (d >> 3) ^ (m & 7);
          ((u16*)P.out)[((size_t)((m >> 10) * Hc + h) * Sc + (m & 1023)) * DKc + c2 * 8 + (d & 7)] = f2bf(v);
        } else {
          float v = acc[mi][ni][j] + P.bias[m];
          int d = m & 63, h = m >> 6, bb = n >> 10, s = n & 1023;
          int c2 = ((s & 63) >> 3) ^ (d & 7);
          ((u16*)P.out)[((size_t)(bb * Hc + h) * DKc + d) * Sc + (s & ~63) + c2 * 8 + (s & 7)] = f2bf(v);
        }
      }
    }
  }
}

// ---------------- fused relative attention ----------------
// R12 structure (grid 1024, 4 waves x 16 q-rows, 8 k-tiles, single-buffered
// K/V, two barriers/tile) with improved T-path: mfma(e,q) gives T[q=cl][er]
// -> ONE aligned b64 store per rc0 (stride 84, uniform banks); gather reads
// Uw[cl*84 + r].
__global__ __launch_bounds__(256, 4) void attn_rel(
    const u16* __restrict__ qg, const u16* __restrict__ kg,
    const u16* __restrict__ vtg, const u16* __restrict__ erg,
    u16* __restrict__ Opart, float* __restrict__ lpart) {
  __shared__ __align__(16) u16 sK[64 * 64];
  __shared__ __align__(16) u16 sV[64 * 64];
  __shared__ __align__(16) u16 sU[4][1344];  // union: T [16][84] / P [16][76]
  const int tid = threadIdx.x, lane = tid & 63, w = tid >> 6;
  const int cl = lane & 15, rg = lane >> 4;
  const int key = cl & 7;
  const int bh = blockIdx.x & 31, qt = (blockIdx.x >> 5) & 15, half = blockIdx.x >> 9;
  const int q0 = qt * 64, t0 = half * 8;

  const u16* qrow = qg + ((size_t)bh * Sc + q0 + w * 16 + cl) * DKc;
  bf16x8 qf0 = *(const bf16x8*)(qrow + (rg ^ key) * 8);
  bf16x8 qf1 = *(const bf16x8*)(qrow + ((rg + 4) ^ key) * 8);
  f32x4 oacc[4] = {};
  float lsum = 0.f;
  u16* Uw = sU[w];
  const u16* kbase = kg + (size_t)bh * Sc * DKc;
  const u16* vbase = vtg + (size_t)bh * DKc * Sc;

  auto stage = [&](int t) {
    const u16* ks = kbase + t * 64 * 64;
    #pragma unroll
    for (int i = 0; i < 2; ++i) {
      GLDS16(ks + (i * 32 + w * 8) * 64 + lane * 8, &sK[(i * 32 + w * 8) * 64]);
      GLDS16(vbase + (size_t)(i * 32 + w * 8 + (lane >> 3)) * Sc + t * 64 + (lane & 7) * 8,
             &sV[(i * 32 + w * 8) * 64]);
    }
  };

  stage(t0);
  for (int tt = 0; tt < 8; ++tt) {
    const int t = t0 + tt;
    __syncthreads();  // staging visible (each wave drained own vmcnt at barrier)

    // S^T = K . Q^T : lane (cl,rg) reg j = S[q0+w16+cl][k0+nc*16+rg*4+j]
    f32x4 sct[4];
    #pragma unroll
    for (int nc = 0; nc < 4; ++nc) {
      const u16* kr = sK + (nc * 16 + cl) * 64;
      bf16x8 b0 = *(const bf16x8*)(kr + (rg ^ key) * 8);
      bf16x8 b1 = *(const bf16x8*)(kr + ((rg + 4) ^ key) * 8);
      f32x4 a = {};
      a = __builtin_amdgcn_mfma_f32_16x16x32_bf16(b0, qf0, a, 0, 0, 0);
      a = __builtin_amdgcn_mfma_f32_16x16x32_bf16(b1, qf1, a, 0, 0, 0);
      sct[nc] = a;
    }
    // T = Q . Er_win^T via mfma(e, q): lane (cl,rg) reg j =
    // T[q=cl][er = rc0*16 + rg*4 + j] -> one aligned b64 store per rc0.
    const u16* ebase = erg + (size_t)(q0 + w * 16 - t * 64 + 960) * DKc;
    #pragma unroll
    for (int rc0 = 0; rc0 < 5; ++rc0) {
      const u16* er = ebase + (size_t)(rc0 * 16 + cl) * DKc;
      bf16x8 e0 = *(const bf16x8*)(er + (rg ^ key) * 8);
      bf16x8 e1 = *(const bf16x8*)(er + ((rg + 4) ^ key) * 8);
      f32x4 a = {};
      a = __builtin_amdgcn_mfma_f32_16x16x32_bf16(e0, qf0, a, 0, 0, 0);
      a = __builtin_amdgcn_mfma_f32_16x16x32_bf16(e1, qf1, a, 0, 0, 0);
      ushort4 pk4;
      pk4.x = f2bf(a[0]); pk4.y = f2bf(a[1]);
      pk4.z = f2bf(a[2]); pk4.w = f2bf(a[3]);
      *(ushort4*)(Uw + cl * 84 + rc0 * 16 + rg * 4) = pk4;
    }
    // gather rel term + exp (no max needed: |s| bounded ~6)
    float pv[4][4];
    #pragma unroll
    for (int nc = 0; nc < 4; ++nc) {
      #pragma unroll
      for (int j = 0; j < 4; ++j) {
        int r = cl + 63 - (nc * 16 + rg * 4 + j);  // in [0,78]
        float tval = bf2f(Uw[cl * 84 + r]);
        float p = __expf((sct[nc][j] + tval) * 0.125f);
        lsum += p;
        pv[nc][j] = p;
      }
    }
    // P[q=cl][k] stores: j-contiguous -> b64 (overwrites T region, gathers done)
    #pragma unroll
    for (int nc = 0; nc < 4; ++nc) {
      ushort4 pk;
      pk.x = f2bf(pv[nc][0]); pk.y = f2bf(pv[nc][1]);
      pk.z = f2bf(pv[nc][2]); pk.w = f2bf(pv[nc][3]);
      *(ushort4*)(Uw + cl * 76 + nc * 16 + rg * 4) = pk;
    }
    bf16x8 pa0 = *(const bf16x8*)(Uw + cl * 76 + rg * 8);
    bf16x8 pa1 = *(const bf16x8*)(Uw + cl * 76 + 32 + rg * 8);
    #pragma unroll
    for (int dc = 0; dc < 4; ++dc) {
      const u16* vr = sV + (dc * 16 + cl) * 64;
      bf16x8 b0 = *(const bf16x8*)(vr + (rg ^ key) * 8);
      bf16x8 b1 = *(const bf16x8*)(vr + ((rg + 4) ^ key) * 8);
      oacc[dc] = __builtin_amdgcn_mfma_f32_16x16x32_bf16(pa0, b0, oacc[dc], 0, 0, 0);
      oacc[dc] = __builtin_amdgcn_mfma_f32_16x16x32_bf16(pa1, b1, oacc[dc], 0, 0, 0);
    }
    __syncthreads();  // all waves done reading sK/sV
    if (tt < 7) stage(t + 1);
  }
  // l[q=cl]: sum across the 4 rg-groups
  lsum += __shfl_xor(lsum, 16);
  lsum += __shfl_xor(lsum, 32);
  const size_t pb = (size_t)(half * 32 + bh) * Sc;
  if (rg == 0) lpart[pb + q0 + w * 16 + cl] = lsum;
  u16* Ob = Opart + (pb + q0 + w * 16) * DKc;
  #pragma unroll
  for (int dc = 0; dc < 4; ++dc)
    #pragma unroll
    for (int j = 0; j < 4; ++j)
      Ob[(rg * 4 + j) * DKc + dc * 16 + cl] = f2bf(oacc[dc][j]);
}

// ---------------- host ----------------
extern "C" void kernel_launch(void* const* d_in, const int* in_sizes, int n_in,
                              void* d_out, int out_size, void* d_ws, size_t ws_size,
                              hipStream_t stream) {
  (void)in_sizes; (void)n_in; (void)out_size; (void)ws_size;
  const float* query = (const float*)d_in[0];
  const float* key_  = (const float*)d_in[1];
  const float* value = (const float*)d_in[2];
  const float* Wq = (const float*)d_in[3];
  const float* Wk = (const float*)d_in[4];
  const float* Wv = (const float*)d_in[5];
  const float* Wo = (const float*)d_in[6];
  const float* bq = (const float*)d_in[7];
  const float* bk = (const float*)d_in[8];
  const float* bv = (const float*)d_in[9];
  const float* bo = (const float*)d_in[10];
  const float* Er = (const float*)d_in[11];

  char* p = (char*)d_ws;
  size_t off = 0;
  auto alloc = [&](size_t bytes) {
    char* r = p + off;
    off += (bytes + 255) & ~(size_t)255;
    return r;
  };
  u16* Xq  = (u16*)alloc((size_t)2048 * 1024 * 2);
  u16* Xk  = (u16*)alloc((size_t)2048 * 1024 * 2);
  u16* Xv  = (u16*)alloc((size_t)2048 * 1024 * 2);
  u16* Wqb = (u16*)alloc((size_t)1024 * 1024 * 2);
  u16* Wkb = (u16*)alloc((size_t)1024 * 1024 * 2);
  u16* Wvb = (u16*)alloc((size_t)1024 * 1024 * 2);
  u16* Wob = (u16*)alloc((size_t)1024 * 1024 * 2);
  u16* Erb = (u16*)alloc((size_t)2048 * 64 * 2);
  u16* qh  = (u16*)alloc((size_t)2048 * 1024 * 2);   // [bh][s][64] swz
  u16* kh  = (u16*)alloc((size_t)2048 * 1024 * 2);   // [bh][s][64] swz
  u16* vt  = (u16*)alloc((size_t)2048 * 1024 * 2);   // [bh][64][s] swz
  u16* Opart = (u16*)alloc((size_t)2 * 32 * 1024 * 64 * 2); // bf16 partials
  float* lpart = (float*)alloc((size_t)2 * 32 * 1024 * 4);

  CvtArgs ca;
  ca.j[0] = {query, Xq, 7, 262144};
  ca.j[1] = {key_,  Xk, 7, 262144};
  ca.j[2] = {value, Xv, 7, 262144};
  ca.j[3] = {Wq, Wqb, 7, 131072};
  ca.j[4] = {Wk, Wkb, 7, 131072};
  ca.j[5] = {Wv, Wvb, 7, 131072};
  ca.j[6] = {Wo, Wob, 7, 131072};
  ca.j[7] = {Er, Erb, 3, 16376};  // zero-fills spare row 2047
  ca.cum[0] = 262144;  ca.cum[1] = 524288;  ca.cum[2] = 786432;
  ca.cum[3] = 917504;  ca.cum[4] = 1048576; ca.cum[5] = 1179648;
  ca.cum[6] = 1310720; ca.cum[7] = 1327104;
  cvt_kernel<<<dim3(5184, 1, 1), 256, 0, stream>>>(ca);

  GemmArgs gp;
  gp.p[0] = {Xq, Wqb, bq, (void*)qh, nullptr};
  gp.p[1] = {Xk, Wkb, bk, (void*)kh, nullptr};
  gp.p[2] = {Wvb, Xv, bv, (void*)vt, nullptr};
  gemm_bt<64, 128, 0><<<dim3(768, 1, 1), 256, 0, stream>>>(gp);

  attn_rel<<<dim3(1024, 1, 1), 256, 0, stream>>>(qh, kh, vt, Erb, Opart, lpart);

  GemmArgs go;
  go.p[0] = {Opart, Wob, bo, d_out, lpart};
  go.p[1] = go.p[0];
  go.p[2] = go.p[0];
  gemm_bt<64, 64, 1><<<dim3(512, 1, 1), 256, 0, stream>>>(go);
}

// Round 18
// 90.652 us; speedup vs baseline: 1.0621x; 1.0621x over previous
//
#include <hip/hip_runtime.h>
#include <hip/hip_bf16.h>
#include <cstdint>
#include <cstddef>

typedef __attribute__((ext_vector_type(8))) short bf16x8;
typedef __attribute__((ext_vector_type(4))) float f32x4;
typedef unsigned short u16;
typedef unsigned int u32;

#define DEV static __device__ __forceinline__

constexpr int Sc = 1024, DMc = 1024, Hc = 16, DKc = 64;

DEV u16 f2bf(float f) {
  u32 u = __float_as_uint(f);
  return (u16)((u + 0x7FFFu + ((u >> 16) & 1u)) >> 16);
}
DEV float bf2f(u16 h) { return __uint_as_float(((u32)h) << 16); }

DEV u32 cvtpk(float a, float b) {  // low16 = bf16(a), high16 = bf16(b), RNE (HW)
  // NOTE: inputs must be VALU/memory-sourced, NOT raw MFMA results — the
  // inline asm read of an MFMA dst bypasses the compiler's MFMA->VALU
  // hazard handling (R16/R17 NaN root cause).
  u32 r;
  asm("v_cvt_pk_bf16_f32 %0, %1, %2" : "=v"(r) : "v"(a), "v"(b));
  return r;
}

// async global->LDS: 16B/lane, LDS dest = wave-uniform base + lane*16
#define GLDS16(g, l)                                                        \
  __builtin_amdgcn_global_load_lds(                                         \
      (const __attribute__((address_space(1))) void*)(g),                   \
      (__attribute__((address_space(3))) void*)(l), 16, 0, 0)

// ---------------- f32 -> bf16 + chunk-swizzle conversion ----------------
// Flat-packed: 8 jobs, job boundaries multiples of 256 chunks.
// Within each 64-elem (128B) block, 16B chunk c stored at c ^ (row & 7).
// Chunks in [nreal, nchunk) write zeros (Er spare row).
struct CvtJob { const float* in; u16* out; int rsh; int nreal; };
struct CvtArgs { CvtJob j[8]; int cum[8]; };

__global__ __launch_bounds__(256) void cvt_kernel(CvtArgs a) {
  int g = (int)(blockIdx.x * 256 + threadIdx.x);
  int jb = 0, base = 0;
  #pragma unroll
  for (int k = 0; k < 7; ++k) {
    bool m = g >= a.cum[k];
    jb += m ? 1 : 0;
    base = m ? a.cum[k] : base;
  }
  CvtJob job = a.j[jb];
  int ci = g - base;
  bf16x8 o = {};
  if (ci < job.nreal) {
    const float* src = job.in + (size_t)ci * 8;
    float4 v0 = *(const float4*)src;
    float4 v1 = *(const float4*)(src + 4);
    o[0] = (short)f2bf(v0.x); o[1] = (short)f2bf(v0.y);
    o[2] = (short)f2bf(v0.z); o[3] = (short)f2bf(v0.w);
    o[4] = (short)f2bf(v1.x); o[5] = (short)f2bf(v1.y);
    o[6] = (short)f2bf(v1.z); o[7] = (short)f2bf(v1.w);
  }
  int row = ci >> job.rsh;
  int co = (ci & ~7) | ((ci & 7) ^ (row & 7));
  *(bf16x8*)(job.out + (size_t)co * 8) = o;
}

// ---------------- GEMM: C = A(MxK) * W(NxK)^T + bias, K=1024 -------------
// (R12 structure: chunk-swizzled operands, GLDS16 staging, XCD-aware maps,
//  MODE 1 = out-proj with fused Opart merge; merge pack via HW cvt_pk on
//  VALU-sourced values — R6-proven pattern; __syncthreads separates commit
//  from the fragment reads.)
struct GemmJob { const u16* A; const u16* W; const float* bias; void* out; const float* aux; };
struct GemmArgs { GemmJob p[3]; };

template<int BM, int BN, int MODE>
__global__ __launch_bounds__(256, 2) void gemm_bt(GemmArgs G) {
  constexpr int MI = BM / 32, NI = BN / 32;
  __shared__ __align__(16) u16 sA[2][BM * 64];
  __shared__ __align__(16) u16 sB[2][BN * 64];
  const int tid = threadIdx.x, lane = tid & 63, w = tid >> 6;
  const int cl = lane & 15, rg = lane >> 4;
  const int srow = lane >> 3, schk = lane & 7;
  int z, m0, n0;
  if (MODE == 0) {
    int id = blockIdx.x;
    if (id < 512) {
      z = id >> 8;
      int r = id & 255, xcd = r & 7, t = r >> 3;
      m0 = (xcd * 4 + (t & 3)) * 64;
      n0 = (t >> 2) * 128;
    } else {
      z = 2;
      int r = id - 512, xcd = r & 7, t = r >> 3;
      n0 = (xcd * 2 + (t & 1)) * 128;
      m0 = (t >> 1) * 64;
    }
  } else {
    z = 0;
    int id = blockIdx.x, xcd = id & 7, t = id >> 3;
    m0 = (xcd * 4 + (t & 3)) * 64;
    n0 = (t >> 2) * 64;
  }
  GemmJob P = G.p[z];
  constexpr int K = 1024;
  const int wm = (w >> 1) * (BM / 2), wn = (w & 1) * (BN / 2);
  f32x4 acc[MI][NI] = {};

  bf16x8 ma[2][2];
  float  ml[2][2];

  auto stage = [&](int kt, int b) {
    if (MODE == 0) {
      const u16* Ab = P.A + (size_t)m0 * K + kt * 64;
      #pragma unroll
      for (int i = 0; i < BM / 32; ++i)
        GLDS16(Ab + (size_t)(i * 32 + w * 8 + srow) * K + schk * 8, &sA[b][(i * 32 + w * 8) * 64]);
    } else {
      #pragma unroll
      for (int i = 0; i < 2; ++i) {
        int ch = i * 256 + tid, row = ch >> 3, c = ch & 7;
        int rgl = m0 + row, bb = rgl >> 10, s = rgl & 1023;
        const u16* o0 = P.A + ((size_t)(bb * 16 + kt) * 1024 + s) * 64 + c * 8;
        ma[i][0] = *(const bf16x8*)o0;
        ma[i][1] = *(const bf16x8*)(o0 + (size_t)32 * 1024 * 64);
        ml[i][0] = P.aux[(size_t)(bb * 16 + kt) * 1024 + s];
        ml[i][1] = P.aux[(size_t)(32 + bb * 16 + kt) * 1024 + s];
      }
    }
    const u16* Wb = P.W + (size_t)n0 * K + kt * 64;
    #pragma unroll
    for (int i = 0; i < BN / 32; ++i)
      GLDS16(Wb + (size_t)(i * 32 + w * 8 + srow) * K + schk * 8, &sB[b][(i * 32 + w * 8) * 64]);
  };

  auto commit = [&](int b) {  // MODE 1 only: merge + HW-pack -> swizzled sA
    #pragma unroll
    for (int i = 0; i < 2; ++i) {
      int ch = i * 256 + tid, row = ch >> 3, c = ch & 7;
      float rinv = 1.0f / (ml[i][0] + ml[i][1]);
      u32 pk[4];
      #pragma unroll
      for (int p = 0; p < 4; ++p) {
        float v0 = (bf2f((u16)ma[i][0][2 * p])     + bf2f((u16)ma[i][1][2 * p]))     * rinv;
        float v1 = (bf2f((u16)ma[i][0][2 * p + 1]) + bf2f((u16)ma[i][1][2 * p + 1])) * rinv;
        pk[p] = cvtpk(v0, v1);
      }
      bf16x8 v8;
      #pragma unroll
      for (int p = 0; p < 4; ++p) {
        v8[2 * p]     = (short)(pk[p] & 0xFFFF);
        v8[2 * p + 1] = (short)(pk[p] >> 16);
      }
      *(bf16x8*)(sA[b] + row * 64 + (c ^ (row & 7)) * 8) = v8;
    }
  };

  stage(0, 0);
  if (MODE == 1) commit(0);
  for (int kt = 0; kt < 16; ++kt) {
    __syncthreads();
    const int b = kt & 1;
    if (kt < 15) stage(kt + 1, b ^ 1);
    const u16* A_ = sA[b];
    const u16* B_ = sB[b];
    #pragma unroll
    for (int kk = 0; kk < 2; ++kk) {
      bf16x8 af[MI], bfr[NI];
      #pragma unroll
      for (int mi = 0; mi < MI; ++mi) {
        int row = wm + mi * 16 + cl;
        af[mi] = *(const bf16x8*)(A_ + row * 64 + ((kk * 4 + rg) ^ (row & 7)) * 8);
      }
      #pragma unroll
      for (int ni = 0; ni < NI; ++ni) {
        int row = wn + ni * 16 + cl;
        bfr[ni] = *(const bf16x8*)(B_ + row * 64 + ((kk * 4 + rg) ^ (row & 7)) * 8);
      }
      #pragma unroll
      for (int mi = 0; mi < MI; ++mi)
        #pragma unroll
        for (int ni = 0; ni < NI; ++ni)
          acc[mi][ni] = __builtin_amdgcn_mfma_f32_16x16x32_bf16(af[mi], bfr[ni], acc[mi][ni], 0, 0, 0);
    }
    if (MODE == 1 && kt < 15) commit(b ^ 1);
  }
  #pragma unroll
  for (int mi = 0; mi < MI; ++mi) {
    #pragma unroll
    for (int ni = 0; ni < NI; ++ni) {
      #pragma unroll
      for (int j = 0; j < 4; ++j) {
        int m = m0 + wm + mi * 16 + rg * 4 + j;
        int n = n0 + wn + ni * 16 + cl;
        if (MODE == 1) {
          ((float*)P.out)[(size_t)m * DMc + n] = acc[mi][ni][j] + P.bias[n];
        } else if (z < 2) {
          float v = acc[mi][ni][j] + P.bias[n];
          int h = n >> 6, d = n & 63;
          int c2 = (d >> 3) ^ (m & 7);
          ((u16*)P.out)[((size_t)((m >> 10) * Hc + h) * Sc + (m & 1023)) * DKc + c2 * 8 + (d & 7)] = f2bf(v);
        } else {
          float v = acc[mi][ni][j] + P.bias[m];
          int d = m & 63, h = m >> 6, bb = n >> 10, s = n & 1023;
          int c2 = ((s & 63) >> 3) ^ (d & 7);
          ((u16*)P.out)[((size_t)(bb * Hc + h) * DKc + d) * Sc + (s & ~63) + c2 * 8 + (s & 7)] = f2bf(v);
        }
      }
    }
  }
}

// ---------------- fused relative attention ----------------
// R12 layout/sync exactly (grid 1024, 4 waves x 16 q-rows, 8 k-tiles,
// single-buffered K/V, two barriers/tile; T^T stride-18 via f2bf — MFMA-
// sourced values MUST use the compiler-visible f2bf path, not asm cvtpk).
// P-store packs via HW cvt_pk (VALU-sourced exp results — safe).
__global__ __launch_bounds__(256, 4) void attn_rel(
    const u16* __restrict__ qg, const u16* __restrict__ kg,
    const u16* __restrict__ vtg, const u16* __restrict__ erg,
    u16* __restrict__ Opart, float* __restrict__ lpart) {
  __shared__ __align__(16) u16 sK[64 * 64];
  __shared__ __align__(16) u16 sV[64 * 64];
  __shared__ __align__(16) u16 sU[4][1440];  // union: T^T [80][18] / P [16][76]
  const int tid = threadIdx.x, lane = tid & 63, w = tid >> 6;
  const int cl = lane & 15, rg = lane >> 4;
  const int key = cl & 7;
  const int bh = blockIdx.x & 31, qt = (blockIdx.x >> 5) & 15, half = blockIdx.x >> 9;
  const int q0 = qt * 64, t0 = half * 8;

  const u16* qrow = qg + ((size_t)bh * Sc + q0 + w * 16 + cl) * DKc;
  bf16x8 qf0 = *(const bf16x8*)(qrow + (rg ^ key) * 8);
  bf16x8 qf1 = *(const bf16x8*)(qrow + ((rg + 4) ^ key) * 8);
  f32x4 oacc[4] = {};
  float lsum = 0.f;
  u16* Uw = sU[w];
  const u16* kbase = kg + (size_t)bh * Sc * DKc;
  const u16* vbase = vtg + (size_t)bh * DKc * Sc;

  auto stage = [&](int t) {
    const u16* ks = kbase + t * 64 * 64;
    #pragma unroll
    for (int i = 0; i < 2; ++i) {
      GLDS16(ks + (i * 32 + w * 8) * 64 + lane * 8, &sK[(i * 32 + w * 8) * 64]);
      GLDS16(vbase + (size_t)(i * 32 + w * 8 + (lane >> 3)) * Sc + t * 64 + (lane & 7) * 8,
             &sV[(i * 32 + w * 8) * 64]);
    }
  };

  stage(t0);
  for (int tt = 0; tt < 8; ++tt) {
    const int t = t0 + tt;
    __syncthreads();  // staging visible (each wave drained own vmcnt at barrier)

    // S^T = K . Q^T : lane (cl,rg) reg j = S[q0+w16+cl][k0+nc*16+rg*4+j]
    f32x4 sct[4];
    #pragma unroll
    for (int nc = 0; nc < 4; ++nc) {
      const u16* kr = sK + (nc * 16 + cl) * 64;
      bf16x8 b0 = *(const bf16x8*)(kr + (rg ^ key) * 8);
      bf16x8 b1 = *(const bf16x8*)(kr + ((rg + 4) ^ key) * 8);
      f32x4 a = {};
      a = __builtin_amdgcn_mfma_f32_16x16x32_bf16(b0, qf0, a, 0, 0, 0);
      a = __builtin_amdgcn_mfma_f32_16x16x32_bf16(b1, qf1, a, 0, 0, 0);
      sct[nc] = a;
    }
    // T = Q . Er_win^T -> store T^T[rl][q_local] (stride 18; f2bf path)
    const u16* ebase = erg + (size_t)(q0 + w * 16 - t * 64 + 960) * DKc;
    #pragma unroll
    for (int rc0 = 0; rc0 < 5; ++rc0) {
      const u16* er = ebase + (size_t)(rc0 * 16 + cl) * DKc;
      bf16x8 e0 = *(const bf16x8*)(er + (rg ^ key) * 8);
      bf16x8 e1 = *(const bf16x8*)(er + ((rg + 4) ^ key) * 8);
      f32x4 a = {};
      a = __builtin_amdgcn_mfma_f32_16x16x32_bf16(qf0, e0, a, 0, 0, 0);
      a = __builtin_amdgcn_mfma_f32_16x16x32_bf16(qf1, e1, a, 0, 0, 0);
      u16* tp = Uw + (rc0 * 16 + cl) * 18 + rg * 4;
      ushort2 lo, hi;
      lo.x = f2bf(a[0]); lo.y = f2bf(a[1]);
      hi.x = f2bf(a[2]); hi.y = f2bf(a[3]);
      *(ushort2*)tp = lo;
      *(ushort2*)(tp + 2) = hi;
    }
    __builtin_amdgcn_sched_barrier(0);  // T-stores complete before gathers
    // gather rel term + exp (no max needed: |s| bounded ~6)
    float pv[4][4];
    #pragma unroll
    for (int nc = 0; nc < 4; ++nc) {
      #pragma unroll
      for (int j = 0; j < 4; ++j) {
        int r = cl + 63 - (nc * 16 + rg * 4 + j);  // in [0,78]
        float tval = bf2f(Uw[r * 18 + cl]);
        float p = __expf((sct[nc][j] + tval) * 0.125f);
        lsum += p;
        pv[nc][j] = p;
      }
    }
    __builtin_amdgcn_sched_barrier(0);  // gathers complete before P overwrites T
    // P[q=cl][k] stores: HW-pack (VALU-sourced) -> one b64 (u16-typed access)
    #pragma unroll
    for (int nc = 0; nc < 4; ++nc) {
      uint2 pk2;
      pk2.x = cvtpk(pv[nc][0], pv[nc][1]);
      pk2.y = cvtpk(pv[nc][2], pv[nc][3]);
      *(ushort4*)(Uw + cl * 76 + nc * 16 + rg * 4) = __builtin_bit_cast(ushort4, pk2);
    }
    __builtin_amdgcn_sched_barrier(0);  // P-stores complete before pa reads
    bf16x8 pa0 = *(const bf16x8*)(Uw + cl * 76 + rg * 8);
    bf16x8 pa1 = *(const bf16x8*)(Uw + cl * 76 + 32 + rg * 8);
    #pragma unroll
    for (int dc = 0; dc < 4; ++dc) {
      const u16* vr = sV + (dc * 16 + cl) * 64;
      bf16x8 b0 = *(const bf16x8*)(vr + (rg ^ key) * 8);
      bf16x8 b1 = *(const bf16x8*)(vr + ((rg + 4) ^ key) * 8);
      oacc[dc] = __builtin_amdgcn_mfma_f32_16x16x32_bf16(pa0, b0, oacc[dc], 0, 0, 0);
      oacc[dc] = __builtin_amdgcn_mfma_f32_16x16x32_bf16(pa1, b1, oacc[dc], 0, 0, 0);
    }
    __syncthreads();  // all waves done reading sK/sV
    if (tt < 7) stage(t + 1);
  }
  // l[q=cl]: sum across the 4 rg-groups
  lsum += __shfl_xor(lsum, 16);
  lsum += __shfl_xor(lsum, 32);
  const size_t pb = (size_t)(half * 32 + bh) * Sc;
  if (rg == 0) lpart[pb + q0 + w * 16 + cl] = lsum;
  u16* Ob = Opart + (pb + q0 + w * 16) * DKc;
  #pragma unroll
  for (int dc = 0; dc < 4; ++dc)
    #pragma unroll
    for (int j = 0; j < 4; ++j)
      Ob[(rg * 4 + j) * DKc + dc * 16 + cl] = f2bf(oacc[dc][j]);
}

// ---------------- host ----------------
extern "C" void kernel_launch(void* const* d_in, const int* in_sizes, int n_in,
                              void* d_out, int out_size, void* d_ws, size_t ws_size,
                              hipStream_t stream) {
  (void)in_sizes; (void)n_in; (void)out_size; (void)ws_size;
  const float* query = (const float*)d_in[0];
  const float* key_  = (const float*)d_in[1];
  const float* value = (const float*)d_in[2];
  const float* Wq = (const float*)d_in[3];
  const float* Wk = (const float*)d_in[4];
  const float* Wv = (const float*)d_in[5];
  const float* Wo = (const float*)d_in[6];
  const float* bq = (const float*)d_in[7];
  const float* bk = (const float*)d_in[8];
  const float* bv = (const float*)d_in[9];
  const float* bo = (const float*)d_in[10];
  const float* Er = (const float*)d_in[11];

  char* p = (char*)d_ws;
  size_t off = 0;
  auto alloc = [&](size_t bytes) {
    char* r = p + off;
    off += (bytes + 255) & ~(size_t)255;
    return r;
  };
  u16* Xq  = (u16*)alloc((size_t)2048 * 1024 * 2);
  u16* Xk  = (u16*)alloc((size_t)2048 * 1024 * 2);
  u16* Xv  = (u16*)alloc((size_t)2048 * 1024 * 2);
  u16* Wqb = (u16*)alloc((size_t)1024 * 1024 * 2);
  u16* Wkb = (u16*)alloc((size_t)1024 * 1024 * 2);
  u16* Wvb = (u16*)alloc((size_t)1024 * 1024 * 2);
  u16* Wob = (u16*)alloc((size_t)1024 * 1024 * 2);
  u16* Erb = (u16*)alloc((size_t)2048 * 64 * 2);
  u16* qh  = (u16*)alloc((size_t)2048 * 1024 * 2);   // [bh][s][64] swz
  u16* kh  = (u16*)alloc((size_t)2048 * 1024 * 2);   // [bh][s][64] swz
  u16* vt  = (u16*)alloc((size_t)2048 * 1024 * 2);   // [bh][64][s] swz
  u16* Opart = (u16*)alloc((size_t)2 * 32 * 1024 * 64 * 2); // bf16 partials
  float* lpart = (float*)alloc((size_t)2 * 32 * 1024 * 4);

  CvtArgs ca;
  ca.j[0] = {query, Xq, 7, 262144};
  ca.j[1] = {key_,  Xk, 7, 262144};
  ca.j[2] = {value, Xv, 7, 262144};
  ca.j[3] = {Wq, Wqb, 7, 131072};
  ca.j[4] = {Wk, Wkb, 7, 131072};
  ca.j[5] = {Wv, Wvb, 7, 131072};
  ca.j[6] = {Wo, Wob, 7, 131072};
  ca.j[7] = {Er, Erb, 3, 16376};  // zero-fills spare row 2047
  ca.cum[0] = 262144;  ca.cum[1] = 524288;  ca.cum[2] = 786432;
  ca.cum[3] = 917504;  ca.cum[4] = 1048576; ca.cum[5] = 1179648;
  ca.cum[6] = 1310720; ca.cum[7] = 1327104;
  cvt_kernel<<<dim3(5184, 1, 1), 256, 0, stream>>>(ca);

  GemmArgs gp;
  gp.p[0] = {Xq, Wqb, bq, (void*)qh, nullptr};
  gp.p[1] = {Xk, Wkb, bk, (void*)kh, nullptr};
  gp.p[2] = {Wvb, Xv, bv, (void*)vt, nullptr};
  gemm_bt<64, 128, 0><<<dim3(768, 1, 1), 256, 0, stream>>>(gp);

  attn_rel<<<dim3(1024, 1, 1), 256, 0, stream>>>(qh, kh, vt, Erb, Opart, lpart);

  GemmArgs go;
  go.p[0] = {Opart, Wob, bo, d_out, lpart};
  go.p[1] = go.p[0];
  go.p[2] = go.p[0];
  gemm_bt<64, 64, 1><<<dim3(512, 1, 1), 256, 0, stream>>>(go);
}

// Round 19
// 90.348 us; speedup vs baseline: 1.0657x; 1.0034x over previous
//
#include <hip/hip_runtime.h>
#include <hip/hip_bf16.h>
#include <cstdint>
#include <cstddef>

typedef __attribute__((ext_vector_type(8))) short bf16x8;
typedef __attribute__((ext_vector_type(4))) float f32x4;
typedef unsigned short u16;
typedef unsigned int u32;

#define DEV static __device__ __forceinline__

constexpr int Sc = 1024, DMc = 1024, Hc = 16, DKc = 64;

DEV u16 f2bf(float f) {
  u32 u = __float_as_uint(f);
  return (u16)((u + 0x7FFFu + ((u >> 16) & 1u)) >> 16);
}
DEV float bf2f(u16 h) { return __uint_as_float(((u32)h) << 16); }

DEV u32 cvtpk(float a, float b) {  // low16 = bf16(a), high16 = bf16(b), RNE (HW)
  // NOTE: inputs must be VALU/memory-sourced, NOT raw MFMA results — the
  // inline asm read of an MFMA dst bypasses the compiler's MFMA->VALU
  // hazard handling (R16/R17 NaN root cause).
  u32 r;
  asm("v_cvt_pk_bf16_f32 %0, %1, %2" : "=v"(r) : "v"(a), "v"(b));
  return r;
}

// async global->LDS: 16B/lane, LDS dest = wave-uniform base + lane*16
#define GLDS16(g, l)                                                        \
  __builtin_amdgcn_global_load_lds(                                         \
      (const __attribute__((address_space(1))) void*)(g),                   \
      (__attribute__((address_space(3))) void*)(l), 16, 0, 0)

// ---------------- f32 -> bf16 + chunk-swizzle conversion ----------------
// Flat-packed: 8 jobs, job boundaries multiples of 256 chunks.
// Within each 64-elem (128B) block, 16B chunk c stored at c ^ (row & 7).
// Chunks in [nreal, nchunk) write zeros (Er spare row).
struct CvtJob { const float* in; u16* out; int rsh; int nreal; };
struct CvtArgs { CvtJob j[8]; int cum[8]; };

__global__ __launch_bounds__(256) void cvt_kernel(CvtArgs a) {
  int g = (int)(blockIdx.x * 256 + threadIdx.x);
  int jb = 0, base = 0;
  #pragma unroll
  for (int k = 0; k < 7; ++k) {
    bool m = g >= a.cum[k];
    jb += m ? 1 : 0;
    base = m ? a.cum[k] : base;
  }
  CvtJob job = a.j[jb];
  int ci = g - base;
  bf16x8 o = {};
  if (ci < job.nreal) {
    const float* src = job.in + (size_t)ci * 8;
    float4 v0 = *(const float4*)src;
    float4 v1 = *(const float4*)(src + 4);
    o[0] = (short)f2bf(v0.x); o[1] = (short)f2bf(v0.y);
    o[2] = (short)f2bf(v0.z); o[3] = (short)f2bf(v0.w);
    o[4] = (short)f2bf(v1.x); o[5] = (short)f2bf(v1.y);
    o[6] = (short)f2bf(v1.z); o[7] = (short)f2bf(v1.w);
  }
  int row = ci >> job.rsh;
  int co = (ci & ~7) | ((ci & 7) ^ (row & 7));
  *(bf16x8*)(job.out + (size_t)co * 8) = o;
}

// ---------------- GEMM: C = A(MxK) * W(NxK)^T + bias, K=1024 -------------
// (R12 structure: chunk-swizzled operands, GLDS16 staging, XCD-aware maps,
//  MODE 1 = out-proj with fused Opart merge; merge pack via HW cvt_pk on
//  VALU-sourced values — R6-proven pattern; __syncthreads separates commit
//  from the fragment reads.)
struct GemmJob { const u16* A; const u16* W; const float* bias; void* out; const float* aux; };
struct GemmArgs { GemmJob p[3]; };

template<int BM, int BN, int MODE>
__global__ __launch_bounds__(256, 2) void gemm_bt(GemmArgs G) {
  constexpr int MI = BM / 32, NI = BN / 32;
  __shared__ __align__(16) u16 sA[2][BM * 64];
  __shared__ __align__(16) u16 sB[2][BN * 64];
  const int tid = threadIdx.x, lane = tid & 63, w = tid >> 6;
  const int cl = lane & 15, rg = lane >> 4;
  const int srow = lane >> 3, schk = lane & 7;
  int z, m0, n0;
  if (MODE == 0) {
    int id = blockIdx.x;
    if (id < 512) {
      z = id >> 8;
      int r = id & 255, xcd = r & 7, t = r >> 3;
      m0 = (xcd * 4 + (t & 3)) * 64;
      n0 = (t >> 2) * 128;
    } else {
      z = 2;
      int r = id - 512, xcd = r & 7, t = r >> 3;
      n0 = (xcd * 2 + (t & 1)) * 128;
      m0 = (t >> 1) * 64;
    }
  } else {
    z = 0;
    int id = blockIdx.x, xcd = id & 7, t = id >> 3;
    m0 = (xcd * 4 + (t & 3)) * 64;
    n0 = (t >> 2) * 64;
  }
  GemmJob P = G.p[z];
  constexpr int K = 1024;
  const int wm = (w >> 1) * (BM / 2), wn = (w & 1) * (BN / 2);
  f32x4 acc[MI][NI] = {};

  bf16x8 ma[2][2];
  float  ml[2][2];

  auto stage = [&](int kt, int b) {
    if (MODE == 0) {
      const u16* Ab = P.A + (size_t)m0 * K + kt * 64;
      #pragma unroll
      for (int i = 0; i < BM / 32; ++i)
        GLDS16(Ab + (size_t)(i * 32 + w * 8 + srow) * K + schk * 8, &sA[b][(i * 32 + w * 8) * 64]);
    } else {
      #pragma unroll
      for (int i = 0; i < 2; ++i) {
        int ch = i * 256 + tid, row = ch >> 3, c = ch & 7;
        int rgl = m0 + row, bb = rgl >> 10, s = rgl & 1023;
        const u16* o0 = P.A + ((size_t)(bb * 16 + kt) * 1024 + s) * 64 + c * 8;
        ma[i][0] = *(const bf16x8*)o0;
        ma[i][1] = *(const bf16x8*)(o0 + (size_t)32 * 1024 * 64);
        ml[i][0] = P.aux[(size_t)(bb * 16 + kt) * 1024 + s];
        ml[i][1] = P.aux[(size_t)(32 + bb * 16 + kt) * 1024 + s];
      }
    }
    const u16* Wb = P.W + (size_t)n0 * K + kt * 64;
    #pragma unroll
    for (int i = 0; i < BN / 32; ++i)
      GLDS16(Wb + (size_t)(i * 32 + w * 8 + srow) * K + schk * 8, &sB[b][(i * 32 + w * 8) * 64]);
  };

  auto commit = [&](int b) {  // MODE 1 only: merge + HW-pack -> swizzled sA
    #pragma unroll
    for (int i = 0; i < 2; ++i) {
      int ch = i * 256 + tid, row = ch >> 3, c = ch & 7;
      float rinv = 1.0f / (ml[i][0] + ml[i][1]);
      u32 pk[4];
      #pragma unroll
      for (int p = 0; p < 4; ++p) {
        float v0 = (bf2f((u16)ma[i][0][2 * p])     + bf2f((u16)ma[i][1][2 * p]))     * rinv;
        float v1 = (bf2f((u16)ma[i][0][2 * p + 1]) + bf2f((u16)ma[i][1][2 * p + 1])) * rinv;
        pk[p] = cvtpk(v0, v1);
      }
      bf16x8 v8;
      #pragma unroll
      for (int p = 0; p < 4; ++p) {
        v8[2 * p]     = (short)(pk[p] & 0xFFFF);
        v8[2 * p + 1] = (short)(pk[p] >> 16);
      }
      *(bf16x8*)(sA[b] + row * 64 + (c ^ (row & 7)) * 8) = v8;
    }
  };

  stage(0, 0);
  if (MODE == 1) commit(0);
  for (int kt = 0; kt < 16; ++kt) {
    __syncthreads();
    const int b = kt & 1;
    if (kt < 15) stage(kt + 1, b ^ 1);
    const u16* A_ = sA[b];
    const u16* B_ = sB[b];
    #pragma unroll
    for (int kk = 0; kk < 2; ++kk) {
      bf16x8 af[MI], bfr[NI];
      #pragma unroll
      for (int mi = 0; mi < MI; ++mi) {
        int row = wm + mi * 16 + cl;
        af[mi] = *(const bf16x8*)(A_ + row * 64 + ((kk * 4 + rg) ^ (row & 7)) * 8);
      }
      #pragma unroll
      for (int ni = 0; ni < NI; ++ni) {
        int row = wn + ni * 16 + cl;
        bfr[ni] = *(const bf16x8*)(B_ + row * 64 + ((kk * 4 + rg) ^ (row & 7)) * 8);
      }
      #pragma unroll
      for (int mi = 0; mi < MI; ++mi)
        #pragma unroll
        for (int ni = 0; ni < NI; ++ni)
          acc[mi][ni] = __builtin_amdgcn_mfma_f32_16x16x32_bf16(af[mi], bfr[ni], acc[mi][ni], 0, 0, 0);
    }
    if (MODE == 1 && kt < 15) commit(b ^ 1);
  }
  #pragma unroll
  for (int mi = 0; mi < MI; ++mi) {
    #pragma unroll
    for (int ni = 0; ni < NI; ++ni) {
      #pragma unroll
      for (int j = 0; j < 4; ++j) {
        int m = m0 + wm + mi * 16 + rg * 4 + j;
        int n = n0 + wn + ni * 16 + cl;
        if (MODE == 1) {
          ((float*)P.out)[(size_t)m * DMc + n] = acc[mi][ni][j] + P.bias[n];
        } else if (z < 2) {
          float v = acc[mi][ni][j] + P.bias[n];
          int h = n >> 6, d = n & 63;
          int c2 = (d >> 3) ^ (m & 7);
          ((u16*)P.out)[((size_t)((m >> 10) * Hc + h) * Sc + (m & 1023)) * DKc + c2 * 8 + (d & 7)] = f2bf(v);
        } else {
          float v = acc[mi][ni][j] + P.bias[m];
          int d = m & 63, h = m >> 6, bb = n >> 10, s = n & 1023;
          int c2 = ((s & 63) >> 3) ^ (d & 7);
          ((u16*)P.out)[((size_t)(bb * Hc + h) * DKc + d) * Sc + (s & ~63) + c2 * 8 + (s & 7)] = f2bf(v);
        }
      }
    }
  }
}

// ---------------- fused relative attention ----------------
// R18 exactly, plus T5 s_setprio(1)/(0) around the two pure-MFMA clusters
// (QK^T, PV). 1024 independent blocks at 4/CU sit at different phases, so
// priority keeps the matrix pipe fed while other waves gather/exp/stage.
__global__ __launch_bounds__(256, 4) void attn_rel(
    const u16* __restrict__ qg, const u16* __restrict__ kg,
    const u16* __restrict__ vtg, const u16* __restrict__ erg,
    u16* __restrict__ Opart, float* __restrict__ lpart) {
  __shared__ __align__(16) u16 sK[64 * 64];
  __shared__ __align__(16) u16 sV[64 * 64];
  __shared__ __align__(16) u16 sU[4][1440];  // union: T^T [80][18] / P [16][76]
  const int tid = threadIdx.x, lane = tid & 63, w = tid >> 6;
  const int cl = lane & 15, rg = lane >> 4;
  const int key = cl & 7;
  const int bh = blockIdx.x & 31, qt = (blockIdx.x >> 5) & 15, half = blockIdx.x >> 9;
  const int q0 = qt * 64, t0 = half * 8;

  const u16* qrow = qg + ((size_t)bh * Sc + q0 + w * 16 + cl) * DKc;
  bf16x8 qf0 = *(const bf16x8*)(qrow + (rg ^ key) * 8);
  bf16x8 qf1 = *(const bf16x8*)(qrow + ((rg + 4) ^ key) * 8);
  f32x4 oacc[4] = {};
  float lsum = 0.f;
  u16* Uw = sU[w];
  const u16* kbase = kg + (size_t)bh * Sc * DKc;
  const u16* vbase = vtg + (size_t)bh * DKc * Sc;

  auto stage = [&](int t) {
    const u16* ks = kbase + t * 64 * 64;
    #pragma unroll
    for (int i = 0; i < 2; ++i) {
      GLDS16(ks + (i * 32 + w * 8) * 64 + lane * 8, &sK[(i * 32 + w * 8) * 64]);
      GLDS16(vbase + (size_t)(i * 32 + w * 8 + (lane >> 3)) * Sc + t * 64 + (lane & 7) * 8,
             &sV[(i * 32 + w * 8) * 64]);
    }
  };

  stage(t0);
  for (int tt = 0; tt < 8; ++tt) {
    const int t = t0 + tt;
    __syncthreads();  // staging visible (each wave drained own vmcnt at barrier)

    // S^T = K . Q^T : lane (cl,rg) reg j = S[q0+w16+cl][k0+nc*16+rg*4+j]
    f32x4 sct[4];
    __builtin_amdgcn_s_setprio(1);
    #pragma unroll
    for (int nc = 0; nc < 4; ++nc) {
      const u16* kr = sK + (nc * 16 + cl) * 64;
      bf16x8 b0 = *(const bf16x8*)(kr + (rg ^ key) * 8);
      bf16x8 b1 = *(const bf16x8*)(kr + ((rg + 4) ^ key) * 8);
      f32x4 a = {};
      a = __builtin_amdgcn_mfma_f32_16x16x32_bf16(b0, qf0, a, 0, 0, 0);
      a = __builtin_amdgcn_mfma_f32_16x16x32_bf16(b1, qf1, a, 0, 0, 0);
      sct[nc] = a;
    }
    __builtin_amdgcn_s_setprio(0);
    // T = Q . Er_win^T -> store T^T[rl][q_local] (stride 18; f2bf path —
    // MFMA-sourced values must use the compiler-visible path, not asm cvtpk)
    const u16* ebase = erg + (size_t)(q0 + w * 16 - t * 64 + 960) * DKc;
    #pragma unroll
    for (int rc0 = 0; rc0 < 5; ++rc0) {
      const u16* er = ebase + (size_t)(rc0 * 16 + cl) * DKc;
      bf16x8 e0 = *(const bf16x8*)(er + (rg ^ key) * 8);
      bf16x8 e1 = *(const bf16x8*)(er + ((rg + 4) ^ key) * 8);
      f32x4 a = {};
      a = __builtin_amdgcn_mfma_f32_16x16x32_bf16(qf0, e0, a, 0, 0, 0);
      a = __builtin_amdgcn_mfma_f32_16x16x32_bf16(qf1, e1, a, 0, 0, 0);
      u16* tp = Uw + (rc0 * 16 + cl) * 18 + rg * 4;
      ushort2 lo, hi;
      lo.x = f2bf(a[0]); lo.y = f2bf(a[1]);
      hi.x = f2bf(a[2]); hi.y = f2bf(a[3]);
      *(ushort2*)tp = lo;
      *(ushort2*)(tp + 2) = hi;
    }
    __builtin_amdgcn_sched_barrier(0);  // T-stores complete before gathers
    // gather rel term + exp (no max needed: |s| bounded ~6)
    float pv[4][4];
    #pragma unroll
    for (int nc = 0; nc < 4; ++nc) {
      #pragma unroll
      for (int j = 0; j < 4; ++j) {
        int r = cl + 63 - (nc * 16 + rg * 4 + j);  // in [0,78]
        float tval = bf2f(Uw[r * 18 + cl]);
        float p = __expf((sct[nc][j] + tval) * 0.125f);
        lsum += p;
        pv[nc][j] = p;
      }
    }
    __builtin_amdgcn_sched_barrier(0);  // gathers complete before P overwrites T
    // P[q=cl][k] stores: HW-pack (VALU-sourced) -> one b64 (u16-typed access)
    #pragma unroll
    for (int nc = 0; nc < 4; ++nc) {
      uint2 pk2;
      pk2.x = cvtpk(pv[nc][0], pv[nc][1]);
      pk2.y = cvtpk(pv[nc][2], pv[nc][3]);
      *(ushort4*)(Uw + cl * 76 + nc * 16 + rg * 4) = __builtin_bit_cast(ushort4, pk2);
    }
    __builtin_amdgcn_sched_barrier(0);  // P-stores complete before pa reads
    bf16x8 pa0 = *(const bf16x8*)(Uw + cl * 76 + rg * 8);
    bf16x8 pa1 = *(const bf16x8*)(Uw + cl * 76 + 32 + rg * 8);
    __builtin_amdgcn_s_setprio(1);
    #pragma unroll
    for (int dc = 0; dc < 4; ++dc) {
      const u16* vr = sV + (dc * 16 + cl) * 64;
      bf16x8 b0 = *(const bf16x8*)(vr + (rg ^ key) * 8);
      bf16x8 b1 = *(const bf16x8*)(vr + ((rg + 4) ^ key) * 8);
      oacc[dc] = __builtin_amdgcn_mfma_f32_16x16x32_bf16(pa0, b0, oacc[dc], 0, 0, 0);
      oacc[dc] = __builtin_amdgcn_mfma_f32_16x16x32_bf16(pa1, b1, oacc[dc], 0, 0, 0);
    }
    __builtin_amdgcn_s_setprio(0);
    __syncthreads();  // all waves done reading sK/sV
    if (tt < 7) stage(t + 1);
  }
  // l[q=cl]: sum across the 4 rg-groups
  lsum += __shfl_xor(lsum, 16);
  lsum += __shfl_xor(lsum, 32);
  const size_t pb = (size_t)(half * 32 + bh) * Sc;
  if (rg == 0) lpart[pb + q0 + w * 16 + cl] = lsum;
  u16* Ob = Opart + (pb + q0 + w * 16) * DKc;
  #pragma unroll
  for (int dc = 0; dc < 4; ++dc)
    #pragma unroll
    for (int j = 0; j < 4; ++j)
      Ob[(rg * 4 + j) * DKc + dc * 16 + cl] = f2bf(oacc[dc][j]);
}

// ---------------- host ----------------
extern "C" void kernel_launch(void* const* d_in, const int* in_sizes, int n_in,
                              void* d_out, int out_size, void* d_ws, size_t ws_size,
                              hipStream_t stream) {
  (void)in_sizes; (void)n_in; (void)out_size; (void)ws_size;
  const float* query = (const float*)d_in[0];
  const float* key_  = (const float*)d_in[1];
  const float* value = (const float*)d_in[2];
  const float* Wq = (const float*)d_in[3];
  const float* Wk = (const float*)d_in[4];
  const float* Wv = (const float*)d_in[5];
  const float* Wo = (const float*)d_in[6];
  const float* bq = (const float*)d_in[7];
  const float* bk = (const float*)d_in[8];
  const float* bv = (const float*)d_in[9];
  const float* bo = (const float*)d_in[10];
  const float* Er = (const float*)d_in[11];

  char* p = (char*)d_ws;
  size_t off = 0;
  auto alloc = [&](size_t bytes) {
    char* r = p + off;
    off += (bytes + 255) & ~(size_t)255;
    return r;
  };
  u16* Xq  = (u16*)alloc((size_t)2048 * 1024 * 2);
  u16* Xk  = (u16*)alloc((size_t)2048 * 1024 * 2);
  u16* Xv  = (u16*)alloc((size_t)2048 * 1024 * 2);
  u16* Wqb = (u16*)alloc((size_t)1024 * 1024 * 2);
  u16* Wkb = (u16*)alloc((size_t)1024 * 1024 * 2);
  u16* Wvb = (u16*)alloc((size_t)1024 * 1024 * 2);
  u16* Wob = (u16*)alloc((size_t)1024 * 1024 * 2);
  u16* Erb = (u16*)alloc((size_t)2048 * 64 * 2);
  u16* qh  = (u16*)alloc((size_t)2048 * 1024 * 2);   // [bh][s][64] swz
  u16* kh  = (u16*)alloc((size_t)2048 * 1024 * 2);   // [bh][s][64] swz
  u16* vt  = (u16*)alloc((size_t)2048 * 1024 * 2);   // [bh][64][s] swz
  u16* Opart = (u16*)alloc((size_t)2 * 32 * 1024 * 64 * 2); // bf16 partials
  float* lpart = (float*)alloc((size_t)2 * 32 * 1024 * 4);

  CvtArgs ca;
  ca.j[0] = {query, Xq, 7, 262144};
  ca.j[1] = {key_,  Xk, 7, 262144};
  ca.j[2] = {value, Xv, 7, 262144};
  ca.j[3] = {Wq, Wqb, 7, 131072};
  ca.j[4] = {Wk, Wkb, 7, 131072};
  ca.j[5] = {Wv, Wvb, 7, 131072};
  ca.j[6] = {Wo, Wob, 7, 131072};
  ca.j[7] = {Er, Erb, 3, 16376};  // zero-fills spare row 2047
  ca.cum[0] = 262144;  ca.cum[1] = 524288;  ca.cum[2] = 786432;
  ca.cum[3] = 917504;  ca.cum[4] = 1048576; ca.cum[5] = 1179648;
  ca.cum[6] = 1310720; ca.cum[7] = 1327104;
  cvt_kernel<<<dim3(5184, 1, 1), 256, 0, stream>>>(ca);

  GemmArgs gp;
  gp.p[0] = {Xq, Wqb, bq, (void*)qh, nullptr};
  gp.p[1] = {Xk, Wkb, bk, (void*)kh, nullptr};
  gp.p[2] = {Wvb, Xv, bv, (void*)vt, nullptr};
  gemm_bt<64, 128, 0><<<dim3(768, 1, 1), 256, 0, stream>>>(gp);

  attn_rel<<<dim3(1024, 1, 1), 256, 0, stream>>>(qh, kh, vt, Erb, Opart, lpart);

  GemmArgs go;
  go.p[0] = {Opart, Wob, bo, d_out, lpart};
  go.p[1] = go.p[0];
  go.p[2] = go.p[0];
  gemm_bt<64, 64, 1><<<dim3(512, 1, 1), 256, 0, stream>>>(go);
}